// Round 1
// baseline (214.164 us; speedup 1.0000x reference)
//
#include <hip/hip_runtime.h>
#include <hip/hip_bf16.h>

// Problem constants (from reference): S=32 samples per row.
// out[k, s] = sum over genes g with seq_idx[g]==k of exp(A[gidx[g],s] + 1 - pos[g]*B[gidx[g],s])
//
// Baseline strategy: 32 lanes own one gene (lane = sample index s).
// Scalar per-gene loads (pos, gidx, sidx) are same-address within the 32-lane
// group -> collapse to broadcast requests. A/B rows (128 B each) come from L2
// (A and B total 256 KB, fully cached). Scatter via 32 consecutive-address
// f32 atomicAdds per gene (one 128B line).

__global__ __launch_bounds__(256) void scatter_exp_kernel(
    const float* __restrict__ A,
    const float* __restrict__ B,
    const float* __restrict__ pos,
    const int* __restrict__ gidx,
    const int* __restrict__ sidx,
    float* __restrict__ out,
    int M)
{
    const int lane = threadIdx.x & 31;                                  // sample s
    int group = (int)((blockIdx.x * blockDim.x + threadIdx.x) >> 5);    // gene id
    const int stride = (int)((gridDim.x * blockDim.x) >> 5);

    for (int g = group; g < M; g += stride) {
        const int   gi = gidx[g];
        const int   si = sidx[g];
        const float p  = pos[g];
        const float a  = A[(gi << 5) + lane];
        const float b  = B[(gi << 5) + lane];
        // exp(a + 1 - p*b)
        const float v = __expf(fmaf(-p, b, a + 1.0f));
        atomicAdd(&out[(si << 5) + lane], v);
    }
}

extern "C" void kernel_launch(void* const* d_in, const int* in_sizes, int n_in,
                              void* d_out, int out_size, void* d_ws, size_t ws_size,
                              hipStream_t stream)
{
    const float* A    = (const float*)d_in[0];   // [N,32]
    const float* B    = (const float*)d_in[1];   // [N,32]
    const float* pos  = (const float*)d_in[2];   // [M]
    const int*   gidx = (const int*)d_in[3];     // [M]
    const int*   sidx = (const int*)d_in[4];     // [M]
    float*       out  = (float*)d_out;           // [K,32]

    const int M = in_sizes[2];

    // Output must be zeroed every call: harness poisons it with 0xAA and the
    // kernel accumulates with atomics.
    hipMemsetAsync(d_out, 0, (size_t)out_size * sizeof(float), stream);

    // Grid-stride: 8192 blocks x 256 threads = 64K gene-groups, ~30 genes each.
    const int block = 256;
    const int total_groups_needed = M;                       // one 32-lane group per gene
    int grid = (total_groups_needed * 32 + block - 1) / block;
    if (grid > 8192) grid = 8192;

    scatter_exp_kernel<<<grid, block, 0, stream>>>(A, B, pos, gidx, sidx, out, M);
}